// Round 1
// baseline (39.090 us; speedup 1.0000x reference)
//
#include <hip/hip_runtime.h>
#include <math.h>

#define NLUT 256    // intervals; nodes = NLUT+1. Paired table = 256 float2 = 2 KB.

typedef float f32x4 __attribute__((ext_vector_type(4)));

// Fast tanh via hardware exp: tanh(x) = (e^2x - 1)/(e^2x + 1). ~1e-7 rel err.
__device__ __forceinline__ float fast_tanh(float x) {
    float e = __expf(2.0f * x);
    return __fdividef(e - 1.0f, e + 1.0f);
}

// ---------------------------------------------------------------------------
// Full QCNN evaluation for one scalar input x (the broadcast conv_val).
// Layers: 8->16->16->12->8->4->4->1. Weight pointers point into LDS.
// ---------------------------------------------------------------------------
__device__ __forceinline__ float eval_net(
    float x,
    const float* W_fm, const float* b_fm,
    const float* W_c1, const float* b_c1,
    const float* W_p1, const float* b_p1,
    const float* W_c2, const float* b_c2,
    const float* W_p2, const float* b_p2,
    const float* W_c3, const float* b_c3,
    const float* W_h,  const float* b_h)
{
    float h[16], g[16];
    #pragma unroll
    for (int j = 0; j < 16; ++j) {
        float a = b_fm[j];
        #pragma unroll
        for (int i = 0; i < 8; ++i) a = fmaf(x, W_fm[i * 16 + j], a);
        h[j] = fast_tanh(a);
    }
    #pragma unroll
    for (int j = 0; j < 16; ++j) {
        float a = b_c1[j];
        #pragma unroll
        for (int i = 0; i < 16; ++i) a = fmaf(h[i], W_c1[i * 16 + j], a);
        g[j] = fast_tanh(a);
    }
    #pragma unroll
    for (int j = 0; j < 12; ++j) {
        float a = b_p1[j];
        #pragma unroll
        for (int i = 0; i < 16; ++i) a = fmaf(g[i], W_p1[i * 12 + j], a);
        h[j] = fast_tanh(a);
    }
    #pragma unroll
    for (int j = 0; j < 8; ++j) {
        float a = b_c2[j];
        #pragma unroll
        for (int i = 0; i < 12; ++i) a = fmaf(h[i], W_c2[i * 8 + j], a);
        g[j] = fast_tanh(a);
    }
    #pragma unroll
    for (int j = 0; j < 4; ++j) {
        float a = b_p2[j];
        #pragma unroll
        for (int i = 0; i < 8; ++i) a = fmaf(g[i], W_p2[i * 4 + j], a);
        h[j] = fast_tanh(a);
    }
    #pragma unroll
    for (int j = 0; j < 4; ++j) {
        float a = b_c3[j];
        #pragma unroll
        for (int i = 0; i < 4; ++i) a = fmaf(h[i], W_c3[i * 4 + j], a);
        g[j] = fast_tanh(a);
    }
    float a = b_h[0];
    #pragma unroll
    for (int i = 0; i < 4; ++i) a = fmaf(g[i], W_h[i], a);
    return __fdividef(1.0f, 1.0f + __expf(-a));
}

// ---------------------------------------------------------------------------
// Kernel 1: build PAIRED LUT. lut2[i] = (f(i/N), f((i+1)/N)), i = 0..NLUT-1.
// One block of 256 threads: node i by thread i, node 256 by thread 0.
// Node values identical to the previous scalar-LUT version (bitwise).
// ---------------------------------------------------------------------------
__global__ __launch_bounds__(256) void build_lut_kernel(
    const float* __restrict__ W_fm, const float* __restrict__ b_fm,
    const float* __restrict__ W_c1, const float* __restrict__ b_c1,
    const float* __restrict__ W_p1, const float* __restrict__ b_p1,
    const float* __restrict__ W_c2, const float* __restrict__ b_c2,
    const float* __restrict__ W_p2, const float* __restrict__ b_p2,
    const float* __restrict__ W_c3, const float* __restrict__ b_c3,
    const float* __restrict__ W_h,  const float* __restrict__ b_h,
    float2* __restrict__ lut2)
{
    __shared__ float s[785];
    __shared__ float sv[NLUT + 1];
    for (int j = threadIdx.x; j < 128; j += 256) s[j]       = W_fm[j];
    if (threadIdx.x < 16)                        s[128 + threadIdx.x] = b_fm[threadIdx.x];
    for (int j = threadIdx.x; j < 256; j += 256) s[144 + j] = W_c1[j];
    if (threadIdx.x < 16)                        s[400 + threadIdx.x] = b_c1[threadIdx.x];
    for (int j = threadIdx.x; j < 192; j += 256) s[416 + j] = W_p1[j];
    if (threadIdx.x < 12)                        s[608 + threadIdx.x] = b_p1[threadIdx.x];
    for (int j = threadIdx.x; j < 96;  j += 256) s[620 + j] = W_c2[j];
    if (threadIdx.x < 8)                         s[716 + threadIdx.x] = b_c2[threadIdx.x];
    for (int j = threadIdx.x; j < 32;  j += 256) s[724 + j] = W_p2[j];
    if (threadIdx.x < 4)                         s[756 + threadIdx.x] = b_p2[threadIdx.x];
    for (int j = threadIdx.x; j < 16;  j += 256) s[760 + j] = W_c3[j];
    if (threadIdx.x < 4)                         s[776 + threadIdx.x] = b_c3[threadIdx.x];
    if (threadIdx.x < 4)                         s[780 + threadIdx.x] = W_h[threadIdx.x];
    if (threadIdx.x == 0)                        s[784] = b_h[0];
    __syncthreads();

    const int t = threadIdx.x;
    const float inv = 1.0f / (float)NLUT;

    sv[t] = eval_net((float)t * inv,
                     s + 0,   s + 128, s + 144, s + 400, s + 416, s + 608,
                     s + 620, s + 716, s + 724, s + 756, s + 760, s + 776,
                     s + 780, s + 784);
    if (t == 0) {
        sv[NLUT] = eval_net((float)NLUT * inv,
                            s + 0,   s + 128, s + 144, s + 400, s + 416, s + 608,
                            s + 620, s + 716, s + 724, s + 756, s + 760, s + 776,
                            s + 780, s + 784);
    }
    __syncthreads();

    lut2[t] = make_float2(sv[t], sv[t + 1]);
}

// ---------------------------------------------------------------------------
// Kernel 2: streaming pass, 4-way unrolled for memory-level parallelism.
// Each wave keeps 4 independent data loads in flight (was 1 — the dependent
// load->sigmoid->gather->store chain exposed full HBM latency per sample).
// LUT lookup is ONE 8B dwordx2 from the 2 KB L1-resident paired table
// (was two divergent 4B gathers on the dependent path).
// ---------------------------------------------------------------------------
__device__ __forceinline__ float qcnn_sample(
    f32x4 d, float w0, float w1, float w2, float w3, float cb,
    const float2* __restrict__ lut2)
{
    float logit = fmaf(d.x, w0, fmaf(d.y, w1,
                  fmaf(d.z, w2, fmaf(d.w, w3, cb))));
    float cv = __fdividef(1.0f, 1.0f + __expf(-logit));
    float t = cv * (float)NLUT;          // in [0, NLUT]
    int idx = (int)t;
    idx = idx < NLUT ? idx : (NLUT - 1);
    idx = idx > 0 ? idx : 0;
    float fr = t - (float)idx;
    float2 v = lut2[idx];
    return fmaf(fr, v.y - v.x, v.x);
}

__global__ __launch_bounds__(256) void qcnn_main_kernel(
    const f32x4* __restrict__ data,
    const float* __restrict__ conv_w, const float* __restrict__ conv_b,
    const float2* __restrict__ lut2, float* __restrict__ out, int n)
{
    const float w0 = conv_w[0], w1 = conv_w[1], w2 = conv_w[2], w3 = conv_w[3];
    const float cb = conv_b[0];

    const int tid = blockIdx.x * 256 + threadIdx.x;
    const int stride = gridDim.x * 256;

    int i = tid;
    // Main unrolled-by-4 path: all 4 loads issue before any dependent use.
    for (; i + 3 * stride < n; i += 4 * stride) {
        f32x4 d0 = data[i];
        f32x4 d1 = data[i + stride];
        f32x4 d2 = data[i + 2 * stride];
        f32x4 d3 = data[i + 3 * stride];

        float r0 = qcnn_sample(d0, w0, w1, w2, w3, cb, lut2);
        float r1 = qcnn_sample(d1, w0, w1, w2, w3, cb, lut2);
        float r2 = qcnn_sample(d2, w0, w1, w2, w3, cb, lut2);
        float r3 = qcnn_sample(d3, w0, w1, w2, w3, cb, lut2);

        out[i]              = r0;
        out[i + stride]     = r1;
        out[i + 2 * stride] = r2;
        out[i + 3 * stride] = r3;
    }
    // Tail (empty for B = 4M with 4096x256 grid, kept for robustness).
    for (; i < n; i += stride) {
        out[i] = qcnn_sample(data[i], w0, w1, w2, w3, cb, lut2);
    }
}

extern "C" void kernel_launch(void* const* d_in, const int* in_sizes, int n_in,
                              void* d_out, int out_size, void* d_ws, size_t ws_size,
                              hipStream_t stream) {
    const float* data   = (const float*)d_in[0];
    const float* conv_w = (const float*)d_in[1];
    const float* conv_b = (const float*)d_in[2];
    const float* W_fm = (const float*)d_in[3];  const float* b_fm = (const float*)d_in[4];
    const float* W_c1 = (const float*)d_in[5];  const float* b_c1 = (const float*)d_in[6];
    const float* W_p1 = (const float*)d_in[7];  const float* b_p1 = (const float*)d_in[8];
    const float* W_c2 = (const float*)d_in[9];  const float* b_c2 = (const float*)d_in[10];
    const float* W_p2 = (const float*)d_in[11]; const float* b_p2 = (const float*)d_in[12];
    const float* W_c3 = (const float*)d_in[13]; const float* b_c3 = (const float*)d_in[14];
    const float* W_h  = (const float*)d_in[15]; const float* b_h  = (const float*)d_in[16];
    float* out = (float*)d_out;
    const int B = in_sizes[0] / 4;  // samples; data is B x (1,2,2) = B float4s

    float2* lut2 = (float2*)d_ws;   // needs NLUT*8 = 2048 bytes
    build_lut_kernel<<<1, 256, 0, stream>>>(
        W_fm, b_fm, W_c1, b_c1, W_p1, b_p1, W_c2, b_c2,
        W_p2, b_p2, W_c3, b_c3, W_h, b_h, lut2);

    // 4096 blocks x 256 threads, 4 samples/thread, fully unrolled (no tail).
    qcnn_main_kernel<<<4096, 256, 0, stream>>>(
        (const f32x4*)data, conv_w, conv_b, lut2, out, B);
}

// Round 2
// 29.064 us; speedup vs baseline: 1.3450x; 1.3450x over previous
//
#include <hip/hip_runtime.h>
#include <math.h>

#define NLUT 256    // intervals; nodes = NLUT+1. Paired table = 256 float2 = 2 KB.

typedef float f32x4 __attribute__((ext_vector_type(4)));

// Fast tanh via hardware exp: tanh(x) = (e^2x - 1)/(e^2x + 1). ~1e-7 rel err.
__device__ __forceinline__ float fast_tanh(float x) {
    float e = __expf(2.0f * x);
    return __fdividef(e - 1.0f, e + 1.0f);
}

// ---------------------------------------------------------------------------
// Full QCNN evaluation for one scalar input x (the broadcast conv_val).
// Layers: 8->16->16->12->8->4->4->1. Weight pointers point into LDS.
// ---------------------------------------------------------------------------
__device__ __forceinline__ float eval_net(
    float x,
    const float* W_fm, const float* b_fm,
    const float* W_c1, const float* b_c1,
    const float* W_p1, const float* b_p1,
    const float* W_c2, const float* b_c2,
    const float* W_p2, const float* b_p2,
    const float* W_c3, const float* b_c3,
    const float* W_h,  const float* b_h)
{
    float h[16], g[16];
    #pragma unroll
    for (int j = 0; j < 16; ++j) {
        float a = b_fm[j];
        #pragma unroll
        for (int i = 0; i < 8; ++i) a = fmaf(x, W_fm[i * 16 + j], a);
        h[j] = fast_tanh(a);
    }
    #pragma unroll
    for (int j = 0; j < 16; ++j) {
        float a = b_c1[j];
        #pragma unroll
        for (int i = 0; i < 16; ++i) a = fmaf(h[i], W_c1[i * 16 + j], a);
        g[j] = fast_tanh(a);
    }
    #pragma unroll
    for (int j = 0; j < 12; ++j) {
        float a = b_p1[j];
        #pragma unroll
        for (int i = 0; i < 16; ++i) a = fmaf(g[i], W_p1[i * 12 + j], a);
        h[j] = fast_tanh(a);
    }
    #pragma unroll
    for (int j = 0; j < 8; ++j) {
        float a = b_c2[j];
        #pragma unroll
        for (int i = 0; i < 12; ++i) a = fmaf(h[i], W_c2[i * 8 + j], a);
        g[j] = fast_tanh(a);
    }
    #pragma unroll
    for (int j = 0; j < 4; ++j) {
        float a = b_p2[j];
        #pragma unroll
        for (int i = 0; i < 8; ++i) a = fmaf(g[i], W_p2[i * 4 + j], a);
        h[j] = fast_tanh(a);
    }
    #pragma unroll
    for (int j = 0; j < 4; ++j) {
        float a = b_c3[j];
        #pragma unroll
        for (int i = 0; i < 4; ++i) a = fmaf(h[i], W_c3[i * 4 + j], a);
        g[j] = fast_tanh(a);
    }
    float a = b_h[0];
    #pragma unroll
    for (int i = 0; i < 4; ++i) a = fmaf(g[i], W_h[i], a);
    return __fdividef(1.0f, 1.0f + __expf(-a));
}

// ---------------------------------------------------------------------------
// Kernel 1: build PAIRED LUT, fully parallel (one eval deep — the round-1
// version serialized 2 evals on thread 0 behind a barrier and cost 44 us).
// Block b owns nodes [128b, 128b+128]: 129 parallel evals, then 128 pair
// writes lut2[128b+t] = (f(node t), f(node t+1)). Node 128 is computed by
// both blocks (identical inputs -> identical value, benign).
// ---------------------------------------------------------------------------
__global__ __launch_bounds__(256) void build_lut_kernel(
    const float* __restrict__ W_fm, const float* __restrict__ b_fm,
    const float* __restrict__ W_c1, const float* __restrict__ b_c1,
    const float* __restrict__ W_p1, const float* __restrict__ b_p1,
    const float* __restrict__ W_c2, const float* __restrict__ b_c2,
    const float* __restrict__ W_p2, const float* __restrict__ b_p2,
    const float* __restrict__ W_c3, const float* __restrict__ b_c3,
    const float* __restrict__ W_h,  const float* __restrict__ b_h,
    float2* __restrict__ lut2)
{
    __shared__ float s[785];
    __shared__ float sv[130];
    for (int j = threadIdx.x; j < 128; j += 256) s[j]       = W_fm[j];
    if (threadIdx.x < 16)                        s[128 + threadIdx.x] = b_fm[threadIdx.x];
    for (int j = threadIdx.x; j < 256; j += 256) s[144 + j] = W_c1[j];
    if (threadIdx.x < 16)                        s[400 + threadIdx.x] = b_c1[threadIdx.x];
    for (int j = threadIdx.x; j < 192; j += 256) s[416 + j] = W_p1[j];
    if (threadIdx.x < 12)                        s[608 + threadIdx.x] = b_p1[threadIdx.x];
    for (int j = threadIdx.x; j < 96;  j += 256) s[620 + j] = W_c2[j];
    if (threadIdx.x < 8)                         s[716 + threadIdx.x] = b_c2[threadIdx.x];
    for (int j = threadIdx.x; j < 32;  j += 256) s[724 + j] = W_p2[j];
    if (threadIdx.x < 4)                         s[756 + threadIdx.x] = b_p2[threadIdx.x];
    for (int j = threadIdx.x; j < 16;  j += 256) s[760 + j] = W_c3[j];
    if (threadIdx.x < 4)                         s[776 + threadIdx.x] = b_c3[threadIdx.x];
    if (threadIdx.x < 4)                         s[780 + threadIdx.x] = W_h[threadIdx.x];
    if (threadIdx.x == 0)                        s[784] = b_h[0];
    __syncthreads();

    const int t = threadIdx.x;
    const int base = blockIdx.x * 128;
    const float inv = 1.0f / (float)NLUT;

    if (t < 129) {
        sv[t] = eval_net((float)(base + t) * inv,
                         s + 0,   s + 128, s + 144, s + 400, s + 416, s + 608,
                         s + 620, s + 716, s + 724, s + 756, s + 760, s + 776,
                         s + 780, s + 784);
    }
    __syncthreads();

    if (t < 128) lut2[base + t] = make_float2(sv[t], sv[t + 1]);
}

// ---------------------------------------------------------------------------
// Kernel 2: streaming pass, 4-way unrolled for memory-level parallelism.
// Each wave keeps 4 independent data loads in flight. LUT lookup is ONE
// 8B dwordx2 from the 2 KB L1-resident paired table.
// ---------------------------------------------------------------------------
__device__ __forceinline__ float qcnn_sample(
    f32x4 d, float w0, float w1, float w2, float w3, float cb,
    const float2* __restrict__ lut2)
{
    float logit = fmaf(d.x, w0, fmaf(d.y, w1,
                  fmaf(d.z, w2, fmaf(d.w, w3, cb))));
    float cv = __fdividef(1.0f, 1.0f + __expf(-logit));
    float t = cv * (float)NLUT;          // in [0, NLUT]
    int idx = (int)t;
    idx = idx < NLUT ? idx : (NLUT - 1);
    idx = idx > 0 ? idx : 0;
    float fr = t - (float)idx;
    float2 v = lut2[idx];
    return fmaf(fr, v.y - v.x, v.x);
}

__global__ __launch_bounds__(256) void qcnn_main_kernel(
    const f32x4* __restrict__ data,
    const float* __restrict__ conv_w, const float* __restrict__ conv_b,
    const float2* __restrict__ lut2, float* __restrict__ out, int n)
{
    const float w0 = conv_w[0], w1 = conv_w[1], w2 = conv_w[2], w3 = conv_w[3];
    const float cb = conv_b[0];

    const int tid = blockIdx.x * 256 + threadIdx.x;
    const int stride = gridDim.x * 256;

    int i = tid;
    // Main unrolled-by-4 path: all 4 loads issue before any dependent use.
    for (; i + 3 * stride < n; i += 4 * stride) {
        f32x4 d0 = data[i];
        f32x4 d1 = data[i + stride];
        f32x4 d2 = data[i + 2 * stride];
        f32x4 d3 = data[i + 3 * stride];

        float r0 = qcnn_sample(d0, w0, w1, w2, w3, cb, lut2);
        float r1 = qcnn_sample(d1, w0, w1, w2, w3, cb, lut2);
        float r2 = qcnn_sample(d2, w0, w1, w2, w3, cb, lut2);
        float r3 = qcnn_sample(d3, w0, w1, w2, w3, cb, lut2);

        out[i]              = r0;
        out[i + stride]     = r1;
        out[i + 2 * stride] = r2;
        out[i + 3 * stride] = r3;
    }
    // Tail (empty for B = 4M with 4096x256 grid, kept for robustness).
    for (; i < n; i += stride) {
        out[i] = qcnn_sample(data[i], w0, w1, w2, w3, cb, lut2);
    }
}

extern "C" void kernel_launch(void* const* d_in, const int* in_sizes, int n_in,
                              void* d_out, int out_size, void* d_ws, size_t ws_size,
                              hipStream_t stream) {
    const float* data   = (const float*)d_in[0];
    const float* conv_w = (const float*)d_in[1];
    const float* conv_b = (const float*)d_in[2];
    const float* W_fm = (const float*)d_in[3];  const float* b_fm = (const float*)d_in[4];
    const float* W_c1 = (const float*)d_in[5];  const float* b_c1 = (const float*)d_in[6];
    const float* W_p1 = (const float*)d_in[7];  const float* b_p1 = (const float*)d_in[8];
    const float* W_c2 = (const float*)d_in[9];  const float* b_c2 = (const float*)d_in[10];
    const float* W_p2 = (const float*)d_in[11]; const float* b_p2 = (const float*)d_in[12];
    const float* W_c3 = (const float*)d_in[13]; const float* b_c3 = (const float*)d_in[14];
    const float* W_h  = (const float*)d_in[15]; const float* b_h  = (const float*)d_in[16];
    float* out = (float*)d_out;
    const int B = in_sizes[0] / 4;  // samples; data is B x (1,2,2) = B float4s

    float2* lut2 = (float2*)d_ws;   // needs NLUT*8 = 2048 bytes
    build_lut_kernel<<<2, 256, 0, stream>>>(
        W_fm, b_fm, W_c1, b_c1, W_p1, b_p1, W_c2, b_c2,
        W_p2, b_p2, W_c3, b_c3, W_h, b_h, lut2);

    // 4096 blocks x 256 threads, 4 samples/thread, fully unrolled (no tail).
    qcnn_main_kernel<<<4096, 256, 0, stream>>>(
        (const f32x4*)data, conv_w, conv_b, lut2, out, B);
}

// Round 3
// 28.384 us; speedup vs baseline: 1.3772x; 1.0240x over previous
//
#include <hip/hip_runtime.h>
#include <math.h>

#define NLUT 256    // intervals; nodes = NLUT+1. LDS paired table = 2 KB.

typedef float f32x4 __attribute__((ext_vector_type(4)));

// Fast tanh via hardware exp: tanh(x) = (e^2x - 1)/(e^2x + 1). ~1e-7 rel err.
__device__ __forceinline__ float fast_tanh(float x) {
    float e = __expf(2.0f * x);
    return __fdividef(e - 1.0f, e + 1.0f);
}

// ---------------------------------------------------------------------------
// Full QCNN evaluation for one scalar input x (the broadcast conv_val).
// Layers: 8->16->16->12->8->4->4->1. Weight pointers point into LDS.
// Bitwise identical to all previous rounds.
// ---------------------------------------------------------------------------
__device__ __forceinline__ float eval_net(
    float x,
    const float* W_fm, const float* b_fm,
    const float* W_c1, const float* b_c1,
    const float* W_p1, const float* b_p1,
    const float* W_c2, const float* b_c2,
    const float* W_p2, const float* b_p2,
    const float* W_c3, const float* b_c3,
    const float* W_h,  const float* b_h)
{
    float h[16], g[16];
    #pragma unroll
    for (int j = 0; j < 16; ++j) {
        float a = b_fm[j];
        #pragma unroll
        for (int i = 0; i < 8; ++i) a = fmaf(x, W_fm[i * 16 + j], a);
        h[j] = fast_tanh(a);
    }
    #pragma unroll
    for (int j = 0; j < 16; ++j) {
        float a = b_c1[j];
        #pragma unroll
        for (int i = 0; i < 16; ++i) a = fmaf(h[i], W_c1[i * 16 + j], a);
        g[j] = fast_tanh(a);
    }
    #pragma unroll
    for (int j = 0; j < 12; ++j) {
        float a = b_p1[j];
        #pragma unroll
        for (int i = 0; i < 16; ++i) a = fmaf(g[i], W_p1[i * 12 + j], a);
        h[j] = fast_tanh(a);
    }
    #pragma unroll
    for (int j = 0; j < 8; ++j) {
        float a = b_c2[j];
        #pragma unroll
        for (int i = 0; i < 12; ++i) a = fmaf(h[i], W_c2[i * 8 + j], a);
        g[j] = fast_tanh(a);
    }
    #pragma unroll
    for (int j = 0; j < 4; ++j) {
        float a = b_p2[j];
        #pragma unroll
        for (int i = 0; i < 8; ++i) a = fmaf(g[i], W_p2[i * 4 + j], a);
        h[j] = fast_tanh(a);
    }
    #pragma unroll
    for (int j = 0; j < 4; ++j) {
        float a = b_c3[j];
        #pragma unroll
        for (int i = 0; i < 4; ++i) a = fmaf(h[i], W_c3[i * 4 + j], a);
        g[j] = fast_tanh(a);
    }
    float a = b_h[0];
    #pragma unroll
    for (int i = 0; i < 4; ++i) a = fmaf(g[i], W_h[i], a);
    return __fdividef(1.0f, 1.0f + __expf(-a));
}

// ---------------------------------------------------------------------------
// FUSED kernel. Persistent: 256 blocks x 1024 threads = 1 block/CU.
// Phase 1 (per block, ~1.2 us, concurrent across CUs): stage weights in LDS,
//   257 threads evaluate the LUT nodes, pack into an LDS float2 pair table.
//   Removes the separate build kernel + its launch/serialization (~5 us),
//   and moves the data-dependent gather from divergent L1 VMEM (20-40 lines
//   per wave) to ds_read_b64 (~12 cyc/wave at ~4-way conflicts).
// Phase 2: grid-stride streaming, 4 independent loads in flight per wave.
// Node values and per-sample arithmetic bitwise identical to prior rounds.
// ---------------------------------------------------------------------------
__global__ __launch_bounds__(1024) void qcnn_fused_kernel(
    const f32x4* __restrict__ data,
    const float* __restrict__ conv_w, const float* __restrict__ conv_b,
    const float* __restrict__ W_fm, const float* __restrict__ b_fm,
    const float* __restrict__ W_c1, const float* __restrict__ b_c1,
    const float* __restrict__ W_p1, const float* __restrict__ b_p1,
    const float* __restrict__ W_c2, const float* __restrict__ b_c2,
    const float* __restrict__ W_p2, const float* __restrict__ b_p2,
    const float* __restrict__ W_c3, const float* __restrict__ b_c3,
    const float* __restrict__ W_h,  const float* __restrict__ b_h,
    float* __restrict__ out, int n)
{
    __shared__ float  s[785];
    __shared__ float  sv[NLUT + 1];
    __shared__ float2 lutl[NLUT];

    const int t = threadIdx.x;

    // ---- Phase 1a: stage weights into LDS (same layout as before) ----
    if (t < 128)  s[t]       = W_fm[t];
    if (t < 16)   s[128 + t] = b_fm[t];
    if (t < 256)  s[144 + t] = W_c1[t];
    if (t < 16)   s[400 + t] = b_c1[t];
    if (t < 192)  s[416 + t] = W_p1[t];
    if (t < 12)   s[608 + t] = b_p1[t];
    if (t < 96)   s[620 + t] = W_c2[t];
    if (t < 8)    s[716 + t] = b_c2[t];
    if (t < 32)   s[724 + t] = W_p2[t];
    if (t < 4)    s[756 + t] = b_p2[t];
    if (t < 16)   s[760 + t] = W_c3[t];
    if (t < 4)    s[776 + t] = b_c3[t];
    if (t < 4)    s[780 + t] = W_h[t];
    if (t == 0)   s[784]     = b_h[0];
    __syncthreads();

    // ---- Phase 1b: 257 parallel node evals (one eval deep) ----
    if (t <= NLUT) {
        sv[t] = eval_net((float)t * (1.0f / (float)NLUT),
                         s + 0,   s + 128, s + 144, s + 400, s + 416, s + 608,
                         s + 620, s + 716, s + 724, s + 756, s + 760, s + 776,
                         s + 780, s + 784);
    }
    __syncthreads();
    if (t < NLUT) lutl[t] = make_float2(sv[t], sv[t + 1]);
    __syncthreads();

    // ---- Phase 2: streaming ----
    const float w0 = conv_w[0], w1 = conv_w[1], w2 = conv_w[2], w3 = conv_w[3];
    const float cb = conv_b[0];

    const int tid = blockIdx.x * 1024 + t;
    const int stride = gridDim.x * 1024;

    int i = tid;
    for (; i + 3 * stride < n; i += 4 * stride) {
        f32x4 d0 = data[i];
        f32x4 d1 = data[i + stride];
        f32x4 d2 = data[i + 2 * stride];
        f32x4 d3 = data[i + 3 * stride];

        float r[4];
        f32x4 dd[4] = {d0, d1, d2, d3};
        #pragma unroll
        for (int k = 0; k < 4; ++k) {
            float logit = fmaf(dd[k].x, w0, fmaf(dd[k].y, w1,
                          fmaf(dd[k].z, w2, fmaf(dd[k].w, w3, cb))));
            float cv = __fdividef(1.0f, 1.0f + __expf(-logit));
            float tt = cv * (float)NLUT;          // in [0, NLUT]
            int idx = (int)tt;
            idx = idx < NLUT ? idx : (NLUT - 1);
            idx = idx > 0 ? idx : 0;
            float fr = tt - (float)idx;
            float2 v = lutl[idx];                 // LDS ds_read_b64
            r[k] = fmaf(fr, v.y - v.x, v.x);
        }

        out[i]              = r[0];
        out[i + stride]     = r[1];
        out[i + 2 * stride] = r[2];
        out[i + 3 * stride] = r[3];
    }
    for (; i < n; i += stride) {
        f32x4 d = data[i];
        float logit = fmaf(d.x, w0, fmaf(d.y, w1,
                      fmaf(d.z, w2, fmaf(d.w, w3, cb))));
        float cv = __fdividef(1.0f, 1.0f + __expf(-logit));
        float tt = cv * (float)NLUT;
        int idx = (int)tt;
        idx = idx < NLUT ? idx : (NLUT - 1);
        idx = idx > 0 ? idx : 0;
        float fr = tt - (float)idx;
        float2 v = lutl[idx];
        out[i] = fmaf(fr, v.y - v.x, v.x);
    }
}

extern "C" void kernel_launch(void* const* d_in, const int* in_sizes, int n_in,
                              void* d_out, int out_size, void* d_ws, size_t ws_size,
                              hipStream_t stream) {
    const float* data   = (const float*)d_in[0];
    const float* conv_w = (const float*)d_in[1];
    const float* conv_b = (const float*)d_in[2];
    const float* W_fm = (const float*)d_in[3];  const float* b_fm = (const float*)d_in[4];
    const float* W_c1 = (const float*)d_in[5];  const float* b_c1 = (const float*)d_in[6];
    const float* W_p1 = (const float*)d_in[7];  const float* b_p1 = (const float*)d_in[8];
    const float* W_c2 = (const float*)d_in[9];  const float* b_c2 = (const float*)d_in[10];
    const float* W_p2 = (const float*)d_in[11]; const float* b_p2 = (const float*)d_in[12];
    const float* W_c3 = (const float*)d_in[13]; const float* b_c3 = (const float*)d_in[14];
    const float* W_h  = (const float*)d_in[15]; const float* b_h  = (const float*)d_in[16];
    float* out = (float*)d_out;
    const int B = in_sizes[0] / 4;  // samples; data is B x (1,2,2) = B float4s

    // 256 blocks x 1024 threads: one persistent block per CU, 16 waves/CU.
    // Each block builds the LUT in LDS itself (no separate build kernel).
    qcnn_fused_kernel<<<256, 1024, 0, stream>>>(
        (const f32x4*)data, conv_w, conv_b,
        W_fm, b_fm, W_c1, b_c1, W_p1, b_p1, W_c2, b_c2,
        W_p2, b_p2, W_c3, b_c3, W_h, b_h, out, B);
}

// Round 4
// 24.934 us; speedup vs baseline: 1.5678x; 1.1384x over previous
//
#include <hip/hip_runtime.h>
#include <math.h>

#define NLUT 256    // intervals; nodes = NLUT+1. LDS paired table = 2 KB.

typedef float f32x4 __attribute__((ext_vector_type(4)));

// Fast tanh via hardware exp: tanh(x) = (e^2x - 1)/(e^2x + 1). ~1e-7 rel err.
__device__ __forceinline__ float fast_tanh(float x) {
    float e = __expf(2.0f * x);
    return __fdividef(e - 1.0f, e + 1.0f);
}

// ---------------------------------------------------------------------------
// Full QCNN evaluation for one scalar input x (the broadcast conv_val).
// Layers: 8->16->16->12->8->4->4->1. Weight pointers point into LDS.
// Bitwise identical to all previous rounds.
// ---------------------------------------------------------------------------
__device__ __forceinline__ float eval_net(
    float x,
    const float* W_fm, const float* b_fm,
    const float* W_c1, const float* b_c1,
    const float* W_p1, const float* b_p1,
    const float* W_c2, const float* b_c2,
    const float* W_p2, const float* b_p2,
    const float* W_c3, const float* b_c3,
    const float* W_h,  const float* b_h)
{
    float h[16], g[16];
    #pragma unroll
    for (int j = 0; j < 16; ++j) {
        float a = b_fm[j];
        #pragma unroll
        for (int i = 0; i < 8; ++i) a = fmaf(x, W_fm[i * 16 + j], a);
        h[j] = fast_tanh(a);
    }
    #pragma unroll
    for (int j = 0; j < 16; ++j) {
        float a = b_c1[j];
        #pragma unroll
        for (int i = 0; i < 16; ++i) a = fmaf(h[i], W_c1[i * 16 + j], a);
        g[j] = fast_tanh(a);
    }
    #pragma unroll
    for (int j = 0; j < 12; ++j) {
        float a = b_p1[j];
        #pragma unroll
        for (int i = 0; i < 16; ++i) a = fmaf(g[i], W_p1[i * 12 + j], a);
        h[j] = fast_tanh(a);
    }
    #pragma unroll
    for (int j = 0; j < 8; ++j) {
        float a = b_c2[j];
        #pragma unroll
        for (int i = 0; i < 12; ++i) a = fmaf(h[i], W_c2[i * 8 + j], a);
        g[j] = fast_tanh(a);
    }
    #pragma unroll
    for (int j = 0; j < 4; ++j) {
        float a = b_p2[j];
        #pragma unroll
        for (int i = 0; i < 8; ++i) a = fmaf(g[i], W_p2[i * 4 + j], a);
        h[j] = fast_tanh(a);
    }
    #pragma unroll
    for (int j = 0; j < 4; ++j) {
        float a = b_c3[j];
        #pragma unroll
        for (int i = 0; i < 4; ++i) a = fmaf(h[i], W_c3[i * 4 + j], a);
        g[j] = fast_tanh(a);
    }
    float a = b_h[0];
    #pragma unroll
    for (int i = 0; i < 4; ++i) a = fmaf(g[i], W_h[i], a);
    return __fdividef(1.0f, 1.0f + __expf(-a));
}

// ---------------------------------------------------------------------------
// FUSED kernel, persistent: 256 blocks x 1024 threads = 1 block/CU.
// Phase 1: build the 257-node LUT in LDS (one eval deep, per block).
// Phase 2: streaming with NON-TEMPORAL loads/stores.
//   Rationale: the harness's per-iteration reset is a 256 MiB fill that
//   leaves the ENTIRE Infinity Cache full of dirty poison lines. Normal
//   cacheable streaming allocates L2/L3 lines and force-evicts ~1 dirty
//   line per allocated line -> ~84 MB of hidden HBM writeback on our
//   critical path ((84+84)/6.6 TB/s ~ 25 us = the observed 28 us floor).
//   nt accesses skip L2/L3 allocation: demand drops to the mandatory
//   84 MB (~13 us floor). Zero reuse exists, so nothing is forfeited.
// Math bitwise identical to prior rounds.
// ---------------------------------------------------------------------------
__global__ __launch_bounds__(1024) void qcnn_fused_kernel(
    const f32x4* __restrict__ data,
    const float* __restrict__ conv_w, const float* __restrict__ conv_b,
    const float* __restrict__ W_fm, const float* __restrict__ b_fm,
    const float* __restrict__ W_c1, const float* __restrict__ b_c1,
    const float* __restrict__ W_p1, const float* __restrict__ b_p1,
    const float* __restrict__ W_c2, const float* __restrict__ b_c2,
    const float* __restrict__ W_p2, const float* __restrict__ b_p2,
    const float* __restrict__ W_c3, const float* __restrict__ b_c3,
    const float* __restrict__ W_h,  const float* __restrict__ b_h,
    float* __restrict__ out, int n)
{
    __shared__ float  s[785];
    __shared__ float  sv[NLUT + 1];
    __shared__ float2 lutl[NLUT];

    const int t = threadIdx.x;

    // ---- Phase 1a: stage weights into LDS ----
    if (t < 128)  s[t]       = W_fm[t];
    if (t < 16)   s[128 + t] = b_fm[t];
    if (t < 256)  s[144 + t] = W_c1[t];
    if (t < 16)   s[400 + t] = b_c1[t];
    if (t < 192)  s[416 + t] = W_p1[t];
    if (t < 12)   s[608 + t] = b_p1[t];
    if (t < 96)   s[620 + t] = W_c2[t];
    if (t < 8)    s[716 + t] = b_c2[t];
    if (t < 32)   s[724 + t] = W_p2[t];
    if (t < 4)    s[756 + t] = b_p2[t];
    if (t < 16)   s[760 + t] = W_c3[t];
    if (t < 4)    s[776 + t] = b_c3[t];
    if (t < 4)    s[780 + t] = W_h[t];
    if (t == 0)   s[784]     = b_h[0];
    __syncthreads();

    // ---- Phase 1b: 257 parallel node evals (one eval deep) ----
    if (t <= NLUT) {
        sv[t] = eval_net((float)t * (1.0f / (float)NLUT),
                         s + 0,   s + 128, s + 144, s + 400, s + 416, s + 608,
                         s + 620, s + 716, s + 724, s + 756, s + 760, s + 776,
                         s + 780, s + 784);
    }
    __syncthreads();
    if (t < NLUT) lutl[t] = make_float2(sv[t], sv[t + 1]);
    __syncthreads();

    // ---- Phase 2: non-temporal streaming ----
    const float w0 = conv_w[0], w1 = conv_w[1], w2 = conv_w[2], w3 = conv_w[3];
    const float cb = conv_b[0];

    const int tid = blockIdx.x * 1024 + t;
    const int stride = gridDim.x * 1024;

    int i = tid;
    for (; i + 3 * stride < n; i += 4 * stride) {
        f32x4 d0 = __builtin_nontemporal_load(data + i);
        f32x4 d1 = __builtin_nontemporal_load(data + i + stride);
        f32x4 d2 = __builtin_nontemporal_load(data + i + 2 * stride);
        f32x4 d3 = __builtin_nontemporal_load(data + i + 3 * stride);

        float r[4];
        f32x4 dd[4] = {d0, d1, d2, d3};
        #pragma unroll
        for (int k = 0; k < 4; ++k) {
            float logit = fmaf(dd[k].x, w0, fmaf(dd[k].y, w1,
                          fmaf(dd[k].z, w2, fmaf(dd[k].w, w3, cb))));
            float cv = __fdividef(1.0f, 1.0f + __expf(-logit));
            float tt = cv * (float)NLUT;          // in [0, NLUT]
            int idx = (int)tt;
            idx = idx < NLUT ? idx : (NLUT - 1);
            idx = idx > 0 ? idx : 0;
            float fr = tt - (float)idx;
            float2 v = lutl[idx];                 // LDS ds_read_b64
            r[k] = fmaf(fr, v.y - v.x, v.x);
        }

        __builtin_nontemporal_store(r[0], out + i);
        __builtin_nontemporal_store(r[1], out + i + stride);
        __builtin_nontemporal_store(r[2], out + i + 2 * stride);
        __builtin_nontemporal_store(r[3], out + i + 3 * stride);
    }
    for (; i < n; i += stride) {
        f32x4 d = __builtin_nontemporal_load(data + i);
        float logit = fmaf(d.x, w0, fmaf(d.y, w1,
                      fmaf(d.z, w2, fmaf(d.w, w3, cb))));
        float cv = __fdividef(1.0f, 1.0f + __expf(-logit));
        float tt = cv * (float)NLUT;
        int idx = (int)tt;
        idx = idx < NLUT ? idx : (NLUT - 1);
        idx = idx > 0 ? idx : 0;
        float fr = tt - (float)idx;
        float2 v = lutl[idx];
        __builtin_nontemporal_store(fmaf(fr, v.y - v.x, v.x), out + i);
    }
}

extern "C" void kernel_launch(void* const* d_in, const int* in_sizes, int n_in,
                              void* d_out, int out_size, void* d_ws, size_t ws_size,
                              hipStream_t stream) {
    const float* data   = (const float*)d_in[0];
    const float* conv_w = (const float*)d_in[1];
    const float* conv_b = (const float*)d_in[2];
    const float* W_fm = (const float*)d_in[3];  const float* b_fm = (const float*)d_in[4];
    const float* W_c1 = (const float*)d_in[5];  const float* b_c1 = (const float*)d_in[6];
    const float* W_p1 = (const float*)d_in[7];  const float* b_p1 = (const float*)d_in[8];
    const float* W_c2 = (const float*)d_in[9];  const float* b_c2 = (const float*)d_in[10];
    const float* W_p2 = (const float*)d_in[11]; const float* b_p2 = (const float*)d_in[12];
    const float* W_c3 = (const float*)d_in[13]; const float* b_c3 = (const float*)d_in[14];
    const float* W_h  = (const float*)d_in[15]; const float* b_h  = (const float*)d_in[16];
    float* out = (float*)d_out;
    const int B = in_sizes[0] / 4;  // samples; data is B x (1,2,2) = B float4s

    // 256 blocks x 1024 threads: one persistent block per CU, 16 waves/CU.
    qcnn_fused_kernel<<<256, 1024, 0, stream>>>(
        (const f32x4*)data, conv_w, conv_b,
        W_fm, b_fm, W_c1, b_c1, W_p1, b_p1, W_c2, b_c2,
        W_p2, b_p2, W_c3, b_c3, W_h, b_h, out, B);
}